// Round 23
// baseline (559.943 us; speedup 1.0000x reference)
//
#include <hip/hip_runtime.h>
#include <hip/hip_bf16.h>

#define T_TOK 16384
#define CDIM 3072
#define DDIM 768
#define HDIM 1024
#define NEXP 8
#define NSLOT 33792   // 32768 assignments + 8*128 padding
#define MAXTILE 264   // NSLOT/128
#define AMB_CAP 2048  // repair capacity (n ~1100, deterministic for fixed inputs)
#define AMB2_CAP 256  // f64 stage capacity (n2 ~27)
#define KSPLIT 4
#define NSEG 8

typedef __attribute__((ext_vector_type(8))) short bfrag;
typedef __attribute__((ext_vector_type(4))) float f32x4;
typedef __attribute__((ext_vector_type(4))) float fvec4;

__device__ __forceinline__ unsigned short bf16_rn(float f) {
  union { float f; unsigned u; } v; v.f = f;
  unsigned r = v.u + 0x7fffu + ((v.u >> 16) & 1u);
  return (unsigned short)(r >> 16);
}
__device__ __forceinline__ float bf16_f32(unsigned short h) {
  union { unsigned u; float f; } v; v.u = ((unsigned)h) << 16;
  return v.f;
}
__device__ __forceinline__ float gelu_exact(float x) {
  return 0.5f * x * (1.0f + erff(x * 0.70710678118654752440f));
}
__device__ __forceinline__ void glds16(const void* g, void* l) {
  __builtin_amdgcn_global_load_lds((const __attribute__((address_space(1))) void*)g,
                                   (__attribute__((address_space(3))) void*)l, 16, 0, 0);
}

// ---------------- init ----------------
__global__ void k_init(int* token_list, int* counts, int* cursors, unsigned short* zero_row,
                       int* amb_count, int* amb2_count) {
  int i = blockIdx.x * 256 + threadIdx.x;
  for (int j = i; j < NSLOT; j += 64 * 256) token_list[j] = -1;
  if (i < NEXP) counts[i] = 0;
  if (i < 128) cursors[i] = 0;
  if (i == 0) { *amb_count = 0; *amb2_count = 0; }
  if (i < 1024) zero_row[i] = 0;
}

// ---------------- transpose proj_w -> hi/lo bf16, TILED layout ------------------
__global__ void k_transpose_split(const float* __restrict__ src,   // proj_w [3072][768]
                                  unsigned short* __restrict__ dhi,
                                  unsigned short* __restrict__ dlo) {
  __shared__ unsigned short h[128][72], l[128][72];   // [c_local][n_local]
  int nb2 = blockIdx.x;          // 0..11 : col_blk = nb2>>1, n-half = nb2&1
  int cb = blockIdx.y;           // 0..23 : c0 = cb*128
  int col_blk = nb2 >> 1, nhalf = nb2 & 1;
  int n0 = col_blk * 128 + nhalf * 64;
  int tid = threadIdx.x;
  const float* in = src + (size_t)(cb * 128) * DDIM + n0;
#pragma unroll
  for (int it = 0; it < 8; ++it) {
    int idx = it * 256 + tid;          // 2048 fvec4 (128c x 16 v4)
    int cl = idx >> 4, nv = idx & 15;
    fvec4 v = *(const fvec4*)(in + (size_t)cl * DDIM + nv * 4);
    unsigned long long ph = 0, pl = 0;
#pragma unroll
    for (int e = 0; e < 4; ++e) {
      unsigned short hh = bf16_rn(v[e]);
      unsigned short ll = bf16_rn(v[e] - bf16_f32(hh));
      ph |= (unsigned long long)hh << (16 * e);
      pl |= (unsigned long long)ll << (16 * e);
    }
    *(unsigned long long*)&h[cl][nv * 4] = ph;
    *(unsigned long long*)&l[cl][nv * 4] = pl;
  }
  __syncthreads();
  size_t obase = ((size_t)col_blk * 96 + cb * 4) * 4096;
#pragma unroll
  for (int kt = 0; kt < 4; ++kt) {
    int kg = tid >> 6, rl = tid & 63;
    bfrag oh, ol;
#pragma unroll
    for (int e = 0; e < 8; ++e) {
      int c = kt * 32 + kg * 8 + e;
      oh[e] = (short)h[c][rl];
      ol[e] = (short)l[c][rl];
    }
    size_t gi = obase + ((size_t)kt * 512 + kg * 128 + nhalf * 64 + rl) * 8;
    *(bfrag*)(dhi + gi) = oh;
    *(bfrag*)(dlo + gi) = ol;
  }
}

// ---------------- transpose+cast f32 [z][K][N] -> granule-TILED bf16 ------------
__global__ void k_transpose_tiled(const float* __restrict__ src0,
                                  unsigned short* __restrict__ dst0, int K, int N) {
  __shared__ unsigned short h[128][72];
  int nb2 = blockIdx.x;          // 0..N/64-1
  int cb = blockIdx.y;           // 0..K/128-1
  int z = blockIdx.z;
  int col_blk = nb2 >> 1, nhalf = nb2 & 1;
  int n0 = col_blk * 128 + nhalf * 64;
  int tid = threadIdx.x;
  const float* in = src0 + (size_t)z * K * N + (size_t)(cb * 128) * N + n0;
#pragma unroll
  for (int it = 0; it < 8; ++it) {
    int idx = it * 256 + tid;
    int cl = idx >> 4, nv = idx & 15;
    fvec4 v = *(const fvec4*)(in + (size_t)cl * N + nv * 4);
    unsigned long long ph = 0;
#pragma unroll
    for (int e = 0; e < 4; ++e)
      ph |= (unsigned long long)bf16_rn(v[e]) << (16 * e);
    *(unsigned long long*)&h[cl][nv * 4] = ph;
  }
  __syncthreads();
  size_t obase = (size_t)z * K * N + ((size_t)col_blk * (K / 32) + cb * 4) * 4096;
#pragma unroll
  for (int kt = 0; kt < 4; ++kt) {
    int kg = tid >> 6, rl = tid & 63;
    bfrag oh;
#pragma unroll
    for (int e = 0; e < 8; ++e) oh[e] = (short)h[kt * 32 + kg * 8 + e][rl];
    *(bfrag*)(dst0 + obase + ((size_t)kt * 512 + kg * 128 + nhalf * 64 + rl) * 8) = oh;
  }
}

// ---------------- GEMM1: fused f32->bf16 A cast (reg-staged), 3-buf, counted vmcnt
__launch_bounds__(256, 3)
__global__ void k_gemm1(const float* __restrict__ hidden,         // [16384][3072] f32
                        const unsigned short* __restrict__ Btil,  // [6][96] tiles
                        float* __restrict__ Cout)                 // xw [T][768]
{
  __shared__ unsigned short sA[12288], sB[12288];
  int tid = threadIdx.x;
  int lane = tid & 63, wave = tid >> 6;
  int id = blockIdx.x;                       // 768 blocks
  int swz = (id & 7) * 96 + (id >> 3);       // bijective XCD swizzle, bcol innermost
  int brow = swz / 6, bcol = swz % 6;
  int row0 = brow * 128, col0 = bcol * 128;
  int wm = wave >> 1, wn = wave & 1;

  f32x4 acc[4][4];
#pragma unroll
  for (int i = 0; i < 4; ++i)
#pragma unroll
    for (int j = 0; j < 4; ++j) acc[i][j] = (f32x4){0.f, 0.f, 0.f, 0.f};

  int rsel = lane & 15, kq = lane >> 4;
  const unsigned short* Bt = Btil + (size_t)(bcol * 96) * 4096;
  // A fused cast: thread covers row ar = tid>>1, half ah = tid&1 (16 f32 = 64B contiguous)
  int ar = tid >> 1, ah = tid & 1;
  const float* Abase = hidden + (size_t)(row0 + ar) * CDIM + ah * 16;
  fvec4 ra, rb, rc, rd;

  auto GLDSB = [&](int kt, int b) {
    const unsigned short* bs = Bt + (size_t)kt * 4096;
    int lbase = b * 4096;
    glds16(bs + (size_t)tid * 8, &sB[lbase + (wave * 64) * 8]);
    glds16(bs + (size_t)(256 + tid) * 8, &sB[lbase + (256 + wave * 64) * 8]);
  };
  auto LOADA = [&](int kt) {
    const float* p = Abase + kt * 32;
    ra = *(const fvec4*)(p);
    rb = *(const fvec4*)(p + 4);
    rc = *(const fvec4*)(p + 8);
    rd = *(const fvec4*)(p + 12);
  };
  auto WRITEA = [&](int b) {
    bfrag f0, f1;
#pragma unroll
    for (int e = 0; e < 4; ++e) {
      f0[e]     = (short)bf16_rn(ra[e]);
      f0[4 + e] = (short)bf16_rn(rb[e]);
      f1[e]     = (short)bf16_rn(rc[e]);
      f1[4 + e] = (short)bf16_rn(rd[e]);
    }
    int lb = b * 4096;
    *(bfrag*)&sA[lb + ((2 * ah) * 128 + ar) * 8] = f0;
    *(bfrag*)&sA[lb + ((2 * ah + 1) * 128 + ar) * 8] = f1;
  };

  // prologue: buf0 fully staged, buf1 in flight
  LOADA(0);
  GLDSB(0, 0);
  WRITEA(0);                       // compiler waits ra..rd (A(0)); B(0) stays in flight
  LOADA(1);
  GLDSB(1, 1);
  asm volatile("s_waitcnt lgkmcnt(0)" ::: "memory");
  asm volatile("s_waitcnt vmcnt(6)" ::: "memory");   // A(1)4+B(1)2 younger -> B(0) done
  __builtin_amdgcn_s_barrier();

  int b0 = 0;
  for (int kt = 0; kt < 96; ++kt) {
    if (kt < 95) {
      int bn = b0 + 1; if (bn >= 3) bn -= 3;
      WRITEA(bn);                  // cvt+write A(kt+1); regs loaded last iter
    }
    if (kt < 94) {
      LOADA(kt + 2);
      int bn2 = b0 + 2; if (bn2 >= 3) bn2 -= 3;
      GLDSB(kt + 2, bn2);
    }
    int lb = b0 * 4096;
    bfrag af[4], bf[4];
#pragma unroll
    for (int i = 0; i < 4; ++i) {
      af[i] = *(const bfrag*)&sA[lb + (kq * 128 + wm * 64 + i * 16 + rsel) * 8];
      bf[i] = *(const bfrag*)&sB[lb + (kq * 128 + wn * 64 + i * 16 + rsel) * 8];
    }
#pragma unroll
    for (int i = 0; i < 4; ++i)
#pragma unroll
      for (int j = 0; j < 4; ++j)
        acc[i][j] = __builtin_amdgcn_mfma_f32_16x16x32_bf16(af[i], bf[j], acc[i][j], 0, 0, 0);
    asm volatile("s_waitcnt lgkmcnt(0)" ::: "memory");   // ds_writes drained
    if (kt < 94) asm volatile("s_waitcnt vmcnt(6)" ::: "memory");  // B(kt+1) done
    else         asm volatile("s_waitcnt vmcnt(0)" ::: "memory");
    __builtin_amdgcn_s_barrier();
    b0 = (b0 == 2) ? 0 : b0 + 1;
  }

  int cc = lane & 15, rr = (lane >> 4) * 4;
#pragma unroll
  for (int i = 0; i < 4; ++i)
#pragma unroll
    for (int j = 0; j < 4; ++j)
#pragma unroll
      for (int r = 0; r < 4; ++r) {
        int row = row0 + wm * 64 + i * 16 + rr + r;
        int col = col0 + wn * 64 + j * 16 + cc;
        Cout[(size_t)row * DDIM + col] = acc[i][j][r];
      }
}

// ---------------- LN1 + GELU + router, wave-per-token (flag gap23 < 8e-3) ----------
__launch_bounds__(256)
__global__ void k_ln_router(const float* __restrict__ xw, const float* __restrict__ proj_b,
                            const float* __restrict__ g1, const float* __restrict__ b1v,
                            const float* __restrict__ gate_w, const float* __restrict__ gate_b,
                            unsigned short* __restrict__ seq_b16,
                            int* __restrict__ top_i, float* __restrict__ top_w,
                            int* __restrict__ amb_list, int* __restrict__ amb_count)
{
  int lane = threadIdx.x & 63;
  int t = blockIdx.x * 4 + (threadIdx.x >> 6);
  const float* xr = xw + (size_t)t * DDIM;
  float x0[12];
  float s = 0.f, s2 = 0.f;
#pragma unroll
  for (int j = 0; j < 12; ++j) {
    int d = lane + 64 * j;
    float v = xr[d] + proj_b[d];
    x0[j] = v; s += v; s2 += v * v;
  }
#pragma unroll
  for (int o = 32; o > 0; o >>= 1) { s += __shfl_xor(s, o, 64); s2 += __shfl_xor(s2, o, 64); }
  float mu = s * (1.f / DDIM);
  float rstd = rsqrtf(s2 * (1.f / DDIM) - mu * mu + 1e-5f);
  float acc8[8];
#pragma unroll
  for (int e = 0; e < 8; ++e) acc8[e] = 0.f;
#pragma unroll
  for (int j = 0; j < 12; ++j) {
    int d = lane + 64 * j;
    float y = (x0[j] - mu) * rstd * g1[d] + b1v[d];
    float ge = gelu_exact(y);
    seq_b16[(size_t)t * DDIM + d] = bf16_rn(ge);
    const float* gw = gate_w + (size_t)d * NEXP;
#pragma unroll
    for (int e = 0; e < 8; ++e) acc8[e] += ge * gw[e];
  }
#pragma unroll
  for (int e = 0; e < 8; ++e)
#pragma unroll
    for (int o = 32; o > 0; o >>= 1) acc8[e] += __shfl_xor(acc8[e], o, 64);
  if (lane == 0) {
    float lg[8];
#pragma unroll
    for (int e = 0; e < 8; ++e) lg[e] = acc8[e] + gate_b[e];
    int i0 = 0;
    for (int e = 1; e < 8; ++e) if (lg[e] > lg[i0]) i0 = e;
    int i1 = (i0 == 0) ? 1 : 0;
    for (int e = 0; e < 8; ++e) if (e != i0 && lg[e] > lg[i1]) i1 = e;
    float l2 = -1e30f;
    for (int e = 0; e < 8; ++e) if (e != i0 && e != i1 && lg[e] > l2) l2 = lg[e];
    if (lg[i1] - l2 < 8e-3f) {
      int p = atomicAdd(amb_count, 1);
      if (p < AMB_CAP) amb_list[p] = t;
    }
    float w0 = 1.f / (1.f + expf(lg[i1] - lg[i0]));
    top_i[t * 2] = i0; top_i[t * 2 + 1] = i1;
    top_w[t * 2] = w0; top_w[t * 2 + 1] = 1.f - w0;
  }
}

// ---------------- repair GEMM: 3-term split-bf16, K-split x4, 2-phase dbuf ---------
__launch_bounds__(256, 2)
__global__ void k_repair(const float* __restrict__ hidden,
                         const unsigned short* __restrict__ BTh,   // tiled [6][96]
                         const unsigned short* __restrict__ BTl,
                         const int* __restrict__ amb_list, const int* __restrict__ amb_count,
                         float* __restrict__ xw_fix4)   // [KSPLIT][AMB_CAP][768]
{
  int n = *amb_count; if (n > AMB_CAP) n = AMB_CAP;
  int by = blockIdx.y;
  if (by * 128 >= n) return;
  int bx = blockIdx.x;                 // 0..5
  int z = blockIdx.z;                  // 0..3 K-quarter
  int col0 = bx * 128;
  __shared__ unsigned short sAh[8192], sAl[8192], sBh[8192], sBl[8192];
  __shared__ int tk[128];
  int tid = threadIdx.x, lane = tid & 63, wave = tid >> 6;
  if (tid < 128) tk[tid] = (by * 128 + tid < n) ? amb_list[by * 128 + tid] : -1;
  __syncthreads();
  int wm = wave >> 1, wn = wave & 1;
  f32x4 acc[4][4];
#pragma unroll
  for (int i = 0; i < 4; ++i)
#pragma unroll
    for (int j = 0; j < 4; ++j) acc[i][j] = (f32x4){0.f, 0.f, 0.f, 0.f};
  int rsel = lane & 15, kq = lane >> 4;
  int ktbase = z * 24;
  const unsigned short* Bth = BTh + (size_t)(bx * 96) * 4096;
  const unsigned short* Btl = BTl + (size_t)(bx * 96) * 4096;

  auto STAGE = [&](int kt, int b) {
    int k0 = (ktbase + kt) * 32;
    int lb = b * 4096;
    size_t tb = (size_t)(ktbase + kt) * 4096;
#pragma unroll
    for (int pass = 0; pass < 2; ++pass) {
      int g = pass * 256 + tid;
      int kg = g >> 7, r = g & 127;
      int tok = tk[r];
      fvec4 a0 = (fvec4){0.f, 0.f, 0.f, 0.f}, a1 = a0;
      if (tok >= 0) {
        const float* ap = hidden + (size_t)tok * CDIM + k0 + kg * 8;
        a0 = *(const fvec4*)ap;
        a1 = *(const fvec4*)(ap + 4);
      }
      bfrag hv, lv;
#pragma unroll
      for (int u = 0; u < 8; ++u) {
        float v = (u < 4) ? a0[u] : a1[u - 4];
        unsigned short h = bf16_rn(v);
        hv[u] = (short)h;
        lv[u] = (short)bf16_rn(v - bf16_f32(h));
      }
      *(bfrag*)&sAh[lb + (size_t)g * 8] = hv;
      *(bfrag*)&sAl[lb + (size_t)g * 8] = lv;
      int li = lb + (pass * 256 + wave * 64) * 8;
      glds16(Bth + tb + (size_t)g * 8, &sBh[li]);
      glds16(Btl + tb + (size_t)g * 8, &sBl[li]);
    }
  };

  STAGE(0, 0);
  __syncthreads();
  for (int kt = 0; kt < 24; ++kt) {
    int b = kt & 1;
    if (kt + 1 < 24) STAGE(kt + 1, b ^ 1);
    int lb = b * 4096;
    bfrag ah[4], al[4], bh[4], bl[4];
#pragma unroll
    for (int i = 0; i < 4; ++i) {
      int ra = wm * 64 + i * 16 + rsel;
      ah[i] = *(const bfrag*)&sAh[lb + (kq * 128 + ra) * 8];
      al[i] = *(const bfrag*)&sAl[lb + (kq * 128 + ra) * 8];
      int cb = wn * 64 + i * 16 + rsel;
      bh[i] = *(const bfrag*)&sBh[lb + (kq * 128 + cb) * 8];
      bl[i] = *(const bfrag*)&sBl[lb + (kq * 128 + cb) * 8];
    }
#pragma unroll
    for (int i = 0; i < 4; ++i)
#pragma unroll
      for (int j = 0; j < 4; ++j) {
        acc[i][j] = __builtin_amdgcn_mfma_f32_16x16x32_bf16(ah[i], bh[j], acc[i][j], 0, 0, 0);
        acc[i][j] = __builtin_amdgcn_mfma_f32_16x16x32_bf16(ah[i], bl[j], acc[i][j], 0, 0, 0);
        acc[i][j] = __builtin_amdgcn_mfma_f32_16x16x32_bf16(al[i], bh[j], acc[i][j], 0, 0, 0);
      }
    __syncthreads();
  }
  float* dst = xw_fix4 + (size_t)z * AMB_CAP * DDIM;
  int cc = lane & 15, rr = (lane >> 4) * 4;
#pragma unroll
  for (int i = 0; i < 4; ++i)
#pragma unroll
    for (int j = 0; j < 4; ++j)
#pragma unroll
      for (int r = 0; r < 4; ++r) {
        int row = by * 128 + wm * 64 + i * 16 + rr + r;
        int col = col0 + wn * 64 + j * 16 + cc;
        dst[(size_t)row * DDIM + col] = acc[i][j][r];
      }
}

// ---------------- fix2: re-route ambiguous tokens from precise xw_fix4 ------------
__launch_bounds__(256)
__global__ void k_fix2(const float* __restrict__ xw_fix4, const float* __restrict__ proj_b,
                       const float* __restrict__ g1, const float* __restrict__ b1v,
                       const float* __restrict__ gate_w, const float* __restrict__ gate_b,
                       const int* __restrict__ amb_list, const int* __restrict__ amb_count,
                       int* __restrict__ top_i, float* __restrict__ top_w,
                       int* __restrict__ amb2_list, int* __restrict__ amb2_count)
{
  int n = *amb_count; if (n > AMB_CAP) n = AMB_CAP;
  int lane = threadIdx.x & 63;
  int slot = blockIdx.x * 4 + (threadIdx.x >> 6);
  if (slot >= n) return;
  int t = amb_list[slot];
  const float* p0 = xw_fix4 + (size_t)slot * DDIM;
  const float* p1 = p0 + (size_t)AMB_CAP * DDIM;
  const float* p2 = p1 + (size_t)AMB_CAP * DDIM;
  const float* p3 = p2 + (size_t)AMB_CAP * DDIM;
  float x0[12];
  float s = 0.f, s2 = 0.f;
#pragma unroll
  for (int j = 0; j < 12; ++j) {
    int d = lane + 64 * j;
    float v = ((p0[d] + p1[d]) + (p2[d] + p3[d])) + proj_b[d];
    x0[j] = v; s += v; s2 += v * v;
  }
#pragma unroll
  for (int o = 32; o > 0; o >>= 1) { s += __shfl_xor(s, o, 64); s2 += __shfl_xor(s2, o, 64); }
  float mu = s * (1.f / DDIM);
  float rstd = rsqrtf(s2 * (1.f / DDIM) - mu * mu + 1e-5f);
  float acc8[8];
#pragma unroll
  for (int e = 0; e < 8; ++e) acc8[e] = 0.f;
#pragma unroll
  for (int j = 0; j < 12; ++j) {
    int d = lane + 64 * j;
    float y = (x0[j] - mu) * rstd * g1[d] + b1v[d];
    float ge = gelu_exact(y);
    const float* gw = gate_w + (size_t)d * NEXP;
#pragma unroll
    for (int e = 0; e < 8; ++e) acc8[e] += ge * gw[e];
  }
#pragma unroll
  for (int e = 0; e < 8; ++e)
#pragma unroll
    for (int o = 32; o > 0; o >>= 1) acc8[e] += __shfl_xor(acc8[e], o, 64);
  if (lane == 0) {
    float lg[8];
#pragma unroll
    for (int e = 0; e < 8; ++e) lg[e] = acc8[e] + gate_b[e];
    int i0 = 0;
    for (int e = 1; e < 8; ++e) if (lg[e] > lg[i0]) i0 = e;
    int i1 = (i0 == 0) ? 1 : 0;
    for (int e = 0; e < 8; ++e) if (e != i0 && lg[e] > lg[i1]) i1 = e;
    float l2 = -1e30f;
    for (int e = 0; e < 8; ++e) if (e != i0 && e != i1 && lg[e] > l2) l2 = lg[e];
    if (lg[i1] - l2 < 2e-4f) {
      int p = atomicAdd(amb2_count, 1);
      if (p < AMB2_CAP) amb2_list[p] = t;
    }
    float w0 = 1.f / (1.f + expf(lg[i1] - lg[i0]));
    top_i[t * 2] = i0; top_i[t * 2 + 1] = i1;
    top_w[t * 2] = w0; top_w[t * 2 + 1] = 1.f - w0;
  }
}

// ---------------- f64 proj partials, C-split x8 ----------------
__launch_bounds__(256, 1)
__global__ void k_router_fix(const float* __restrict__ hidden, const float* __restrict__ proj_w,
                             const int* __restrict__ amb2_list, const int* __restrict__ amb2_count,
                             double* __restrict__ xpart)   // [NSEG][AMB2_CAP][768]
{
  __shared__ float hrow[384];
  int tid = threadIdx.x;
  int seg = blockIdx.y;
  int cbase = seg * 384;
  int n = *amb2_count; if (n > AMB2_CAP) n = AMB2_CAP;
  for (int ii = blockIdx.x; ii < n; ii += gridDim.x) {
    int t = amb2_list[ii];
    __syncthreads();
    if (tid < 96)
      *(fvec4*)&hrow[tid * 4] = *(const fvec4*)(hidden + (size_t)t * CDIM + cbase + tid * 4);
    __syncthreads();
    double p0a = 0.0, p0b = 0.0, p1a = 0.0, p1b = 0.0, p2a = 0.0, p2b = 0.0;
    for (int c0 = 0; c0 < 384; c0 += 16) {
      float w0r[16], w1r[16], w2r[16];
      const float* wp = proj_w + (size_t)(cbase + c0) * DDIM + tid;
#pragma unroll
      for (int u = 0; u < 16; ++u) {
        w0r[u] = wp[u * DDIM];
        w1r[u] = wp[u * DDIM + 256];
        w2r[u] = wp[u * DDIM + 512];
      }
#pragma unroll
      for (int u = 0; u < 16; ++u) {
        double h = (double)hrow[c0 + u];
        if (u & 1) { p0b += h * (double)w0r[u]; p1b += h * (double)w1r[u]; p2b += h * (double)w2r[u]; }
        else       { p0a += h * (double)w0r[u]; p1a += h * (double)w1r[u]; p2a += h * (double)w2r[u]; }
      }
    }
    double* xp = xpart + ((size_t)seg * AMB2_CAP + ii) * DDIM;
    xp[tid] = p0a + p0b;
    xp[tid + 256] = p1a + p1b;
    xp[tid + 512] = p2a + p2b;
  }
}

// ---------------- fix3: combine f64 partials, LN + gelu + gate in f64 ------------
__launch_bounds__(256)
__global__ void k_fix3(const double* __restrict__ xpart, const float* __restrict__ proj_b,
                       const float* __restrict__ g1, const float* __restrict__ b1v,
                       const float* __restrict__ gate_w, const float* __restrict__ gate_b,
                       const int* __restrict__ amb2_list, const int* __restrict__ amb2_count,
                       int* __restrict__ top_i, float* __restrict__ top_w)
{
  __shared__ double redA[4], redB[4], red8[4][8];
  int n = *amb2_count; if (n > AMB2_CAP) n = AMB2_CAP;
  int ii = blockIdx.x;
  if (ii >= n) return;
  int t = amb2_list[ii];
  int tid = threadIdx.x, lane = tid & 63, wave = tid >> 6;
  double x[3]; double s = 0.0, s2 = 0.0;
#pragma unroll
  for (int j = 0; j < 3; ++j) {
    int d = tid + 256 * j;
    double acc = (double)proj_b[d];
#pragma unroll
    for (int seg = 0; seg < NSEG; ++seg)
      acc += xpart[((size_t)seg * AMB2_CAP + ii) * DDIM + d];
    x[j] = acc; s += acc; s2 += acc * acc;
  }
#pragma unroll
  for (int o = 32; o > 0; o >>= 1) { s += __shfl_down(s, o, 64); s2 += __shfl_down(s2, o, 64); }
  if (lane == 0) { redA[wave] = s; redB[wave] = s2; }
  __syncthreads();
  double mu = (redA[0] + redA[1] + redA[2] + redA[3]) / DDIM;
  double ms = (redB[0] + redB[1] + redB[2] + redB[3]) / DDIM;
  double rstd = 1.0 / sqrt(ms - mu * mu + 1e-5);
  double a8[8];
#pragma unroll
  for (int e = 0; e < 8; ++e) a8[e] = 0.0;
#pragma unroll
  for (int j = 0; j < 3; ++j) {
    int d = tid + 256 * j;
    double y = (x[j] - mu) * rstd * (double)g1[d] + (double)b1v[d];
    double ge = 0.5 * y * (1.0 + erf(y * 0.7071067811865475244));
#pragma unroll
    for (int e = 0; e < 8; ++e) a8[e] += ge * (double)gate_w[(size_t)d * NEXP + e];
  }
#pragma unroll
  for (int e = 0; e < 8; ++e)
#pragma unroll
    for (int o = 32; o > 0; o >>= 1) a8[e] += __shfl_down(a8[e], o, 64);
  if (lane == 0) {
#pragma unroll
    for (int e = 0; e < 8; ++e) red8[wave][e] = a8[e];
  }
  __syncthreads();
  if (tid == 0) {
    double lg[8];
#pragma unroll
    for (int e = 0; e < 8; ++e)
      lg[e] = red8[0][e] + red8[1][e] + red8[2][e] + red8[3][e] + (double)gate_b[e];
    int i0 = 0;
    for (int e = 1; e < 8; ++e) if (lg[e] > lg[i0]) i0 = e;
    int i1 = (i0 == 0) ? 1 : 0;
    for (int e = 0; e < 8; ++e) if (e != i0 && e != i1 && lg[e] > lg[i1]) i1 = e;
    double w0 = 1.0 / (1.0 + exp(lg[i1] - lg[i0]));
    top_i[t * 2] = i0; top_i[t * 2 + 1] = i1;
    top_w[t * 2] = (float)w0; top_w[t * 2 + 1] = (float)(1.0 - w0);
  }
}

// ---------------- histogram of final top_i (LDS privatized) ----------------
__global__ void k_count(const int* __restrict__ top_i, int* __restrict__ counts) {
  __shared__ int h[NEXP];
  int tid = threadIdx.x;
  if (tid < NEXP) h[tid] = 0;
  __syncthreads();
  for (int i = blockIdx.x * 256 + tid; i < 2 * T_TOK; i += 64 * 256)
    atomicAdd(&h[top_i[i]], 1);
  __syncthreads();
  if (tid < NEXP) atomicAdd(&counts[tid], h[tid]);
}

// ---------------- offsets (single thread) ----------------
__global__ void k_offsets(const int* __restrict__ counts, int* __restrict__ seg_start,
                          int* __restrict__ padded_total, int* __restrict__ tile_expert) {
  if (threadIdx.x != 0 || blockIdx.x != 0) return;
  int st[NEXP], en[NEXP];
  int s = 0;
  for (int e = 0; e < NEXP; ++e) {
    st[e] = s; seg_start[e] = s;
    s += (counts[e] + 127) & ~127;
    en[e] = s;
  }
  *padded_total = s;
  int nt = s >> 7;
  for (int x = 0; x < nt; ++x) {
    int r = x << 7, e = 0;
    for (int q = 0; q < NEXP; ++q) if (r >= st[q] && r < en[q]) e = q;
    tile_expert[x] = e;
  }
}

// ---------------- scatter: block-aggregated cursors ----------------
__global__ void k_scatter(const int* __restrict__ top_i, const int* __restrict__ seg_start,
                          int* __restrict__ cursors, int* __restrict__ token_list,
                          int* __restrict__ slot_of) {
  __shared__ int lc[NEXP];
  __shared__ int lbase[NEXP];
  int tid = threadIdx.x;
  int t = blockIdx.x * 256 + tid;
  if (tid < NEXP) lc[tid] = 0;
  __syncthreads();
  int e0 = top_i[t * 2], e1 = top_i[t * 2 + 1];
  int o0 = atomicAdd(&lc[e0], 1);
  int o1 = atomicAdd(&lc[e1], 1);
  __syncthreads();
  if (tid < NEXP) lbase[tid] = atomicAdd(&cursors[tid << 4], lc[tid]);
  __syncthreads();
  int p0 = seg_start[e0] + lbase[e0] + o0;
  int p1 = seg_start[e1] + lbase[e1] + o1;
  token_list[p0] = t;
  token_list[p1] = t;
  slot_of[t * 2] = p0;
  slot_of[t * 2 + 1] = p1;
}

// ---------------- GEMM2: 128x128, 3-buf, fused gather (per-lane glds16 src) ------
__launch_bounds__(256, 3)
__global__ void k_gemm2(const unsigned short* __restrict__ seqb,   // [T][768] bf16
                        const unsigned short* __restrict__ w1T,    // tiled [E][8][24]
                        const float* __restrict__ b1,              // [E][1024]
                        const int* __restrict__ token_list,
                        const unsigned short* __restrict__ zero_row,
                        const int* __restrict__ tile_expert,
                        const int* __restrict__ padded_total,
                        unsigned short* __restrict__ hbufT)        // tiled [264][32]
{
  // 1-D grid 264*8. XCD slab + bx innermost: 8 consecutive blocks on one XCD
  // share the same A rows (seqb stays in L2), B panel cycles inside.
  int oid = blockIdx.x;                   // 0..2111
  int xcd = oid & 7, w = oid >> 3;        // w: 0..263
  int by = xcd * 33 + (w >> 3);           // 33 tiles per XCD slab
  int bx = w & 7;                         // 0..7 innermost
  if (by * 128 >= *padded_total) return;
  int e = tile_expert[by];
  __shared__ unsigned short smem[24576];  // sA 3x4096, sB 3x4096 (48 KB)
  unsigned short* sA = smem;
  unsigned short* sB = smem + 12288;
  int tid = threadIdx.x, lane = tid & 63, wave = tid >> 6;
  int col0 = bx * 128;
  int wm = wave >> 1, wn = wave & 1;
  f32x4 acc[4][4];
#pragma unroll
  for (int i = 0; i < 4; ++i)
#pragma unroll
    for (int j = 0; j < 4; ++j) acc[i][j] = (f32x4){0.f, 0.f, 0.f, 0.f};
  // fused gather: this thread always stages row r = tid&127 of the A tile.
  int tokreg = token_list[by * 128 + (tid & 127)];
  const unsigned short* a0;  // pass-0 source base (kg = tid>>7)
  const unsigned short* a1;  // pass-1 source base (kg = 2 + (tid>>7))
  int astep;
  if (tokreg >= 0) {
    a0 = seqb + (size_t)tokreg * DDIM + (tid >> 7) * 8;
    a1 = a0 + 16;
    astep = 32;                  // bf16 elems per K-tile along the row
  } else {
    a0 = zero_row + (tid >> 7) * 8;
    a1 = a0 + 16;
    astep = 0;
  }
  const unsigned short* Bt = w1T + (size_t)e * HDIM * DDIM + (size_t)bx * 24 * 4096;
  int rsel = lane & 15, kq = lane >> 4;

  auto STAGE = [&](int kt, int b) {
    int lbase2 = b * 4096;
    size_t tb = (size_t)kt * 4096;
    glds16(a0 + (size_t)kt * astep, &sA[lbase2 + (wave * 64) * 8]);
    glds16(Bt + tb + (size_t)tid * 8, &sB[lbase2 + (wave * 64) * 8]);
    glds16(a1 + (size_t)kt * astep, &sA[lbase2 + (256 + wave * 64) * 8]);
    glds16(Bt + tb + (size_t)(256 + tid) * 8, &sB[lbase2 + (256 + wave * 64) * 8]);
  };

  STAGE(0, 0);
  STAGE(1, 1);
  int b0 = 0;
  for (int kt = 0; kt < 24; ++kt) {
    if (kt < 23) asm volatile("s_waitcnt vmcnt(4)" ::: "memory");
    else         asm volatile("s_waitcnt vmcnt(0)" ::: "memory");
    __builtin_amdgcn_s_barrier();
    if (kt + 2 < 24) {
      int bn = b0 + 2; if (bn >= 3) bn -= 3;
      STAGE(kt + 2, bn);
    }
    int lb = b0 * 4096;
    bfrag af[4], bf[4];
#pragma unroll
    for (int i = 0; i < 4; ++i) {
      af[i] = *(const bfrag*)&sA[lb + (kq * 128 + wm * 64 + i * 16 + rsel) * 8];
      bf[i] = *(const bfrag*)&sB[lb + (kq * 128 + wn * 64 + i * 16 + rsel) * 8];
    }
#pragma unroll
    for (int i = 0; i < 4; ++i)
#pragma unroll
      for (int j = 0; j < 4; ++j)
        acc[i][j] = __builtin_amdgcn_mfma_f32_16x16x32_bf16(af[i], bf[j], acc[i][j], 0, 0, 0);
    b0 = (b0 == 2) ? 0 : b0 + 1;
  }
  // epilogue: stage 128x128 bf16 into LDS granule-linear, then linear 32KB copy.
  __builtin_amdgcn_s_barrier();   // all MFMA reads of smem done
  int cc = lane & 15, rr = (lane >> 4) * 4;
#pragma unroll
  for (int i = 0; i < 4; ++i)
#pragma unroll
    for (int j = 0; j < 4; ++j)
#pragma unroll
      for (int r = 0; r < 4; ++r) {
        int lr = wm * 64 + i * 16 + rr + r;              // local row
        int lc = wn * 64 + j * 16 + cc;                  // local col 0..127
        float x = acc[i][j][r] + b1[(size_t)e * HDIM + col0 + lc];
        int gi = (lc >> 5) * 4096 + ((lc >> 3) & 3) * 1024 + lr * 8 + (lc & 7);
        smem[gi] = bf16_rn(gelu_exact(x));
      }
  __syncthreads();
  unsigned short* dst = hbufT + ((size_t)by * 32 + (col0 >> 5)) * 4096;
#pragma unroll
  for (int it = 0; it < 8; ++it) {
    int idx = it * 256 + tid;                            // bfrag 0..2047
    *(bfrag*)(dst + (size_t)idx * 8) = *(const bfrag*)&smem[idx * 8];
  }
}

// ---------------- GEMM3: 128x128, 3-buf + counted vmcnt, panel-innermost slab ----
__launch_bounds__(256, 3)
__global__ void k_gemm3(const unsigned short* __restrict__ hbufT,  // tiled [264][32]
                        const unsigned short* __restrict__ w2T,    // tiled [E][6][32]
                        const float* __restrict__ b2,              // [E][768]
                        const int* __restrict__ tile_expert,
                        const int* __restrict__ padded_total,
                        unsigned short* __restrict__ eo)           // bf16 [NSLOT][768]
{
  // 1-D grid 264*6. XCD slab + bx innermost (6 consecutive blocks share A tile).
  int oid = blockIdx.x;                   // 0..1583
  int xcd = oid & 7, w = oid >> 3;        // w: 0..197
  int by = xcd * 33 + (w / 6);            // w/6 < 33
  int bx = w % 6;                         // 0..5 innermost
  if (by * 128 >= *padded_total) return;
  int e = tile_expert[by];
  __shared__ unsigned short smem[24576];
  unsigned short* sA = smem;
  unsigned short* sB = smem + 12288;
  int tid = threadIdx.x, lane = tid & 63, wave = tid >> 6;
  int col0 = bx * 128;
  int wm = wave >> 1, wn = wave & 1;
  f32x4 acc[4][4];
#pragma unroll
  for (int i = 0; i < 4; ++i)
#pragma unroll
    for (int j = 0; j < 4; ++j) acc[i][j] = (f32x4){0.f, 0.f, 0.f, 0.f};
  const unsigned short* At = hbufT + (size_t)by * 32 * 4096;
  const unsigned short* Bt = w2T + (size_t)e * DDIM * HDIM + (size_t)bx * 32 * 4096;
  int rsel = lane & 15, kq = lane >> 4;

  auto STAGE = [&](int kt, int b) {
    int lbase2 = b * 4096;
    size_t tb = (size_t)kt * 4096;
#pragma unroll
    for (int pass = 0; pass < 2; ++pass) {
      int g = pass * 256 + tid;
      int li = lbase2 + (pass * 256 + wave * 64) * 8;
      glds16(At + tb + (size_t)g * 8, &sA[li]);
      glds16(Bt + tb + (size_t)g * 8, &sB[li]);
    }
  };

  STAGE(0, 0);
  STAGE(1, 1);
  int b0 = 0;
  for (int kt = 0; kt < 32; ++kt) {
    if (kt < 31) asm volatile("s_waitcnt vmcnt(4)" ::: "memory");
    else         asm volatile("s_waitcnt vmcnt(0)" ::: "memory");
    __builtin_amdgcn_s_barrier();
    if (kt + 2 < 32) {
      int bn = b0 + 2; if (bn >= 3) bn -= 3;
      STAGE(kt + 2, bn);
    }
    int lb = b0 * 4096;
    bfrag af[4], bf[4];
#pragma unroll
    for (int i = 0; i < 4; ++i) {
      af[i] = *(const bfrag*)&sA[lb + (kq * 128 + wm * 64 + i * 16 + rsel) * 8];
      bf[i] = *(const bfrag*)&sB[lb + (kq * 128 + wn * 64 + i * 16 + rsel) * 8];
    }
#pragma unroll
    for (int i = 0; i < 4; ++i)
#pragma unroll
      for (int j = 0; j < 4; ++j)
        acc[i][j] = __builtin_amdgcn_mfma_f32_16x16x32_bf16(af[i], bf[j], acc[i][j], 0, 0, 0);
    b0 = (b0 == 2) ? 0 : b0 + 1;
  }
  // epilogue: stage 128x128 bf16 into LDS row-major, then coalesced row writes.
  __builtin_amdgcn_s_barrier();
  int cc = lane & 15, rr = (lane >> 4) * 4;
#pragma unroll
  for (int i = 0; i < 4; ++i)
#pragma unroll
    for (int j = 0; j < 4; ++j)
#pragma unroll
      for (int r = 0; r < 4; ++r) {
        int lr = wm * 64 + i * 16 + rr + r;
        int lc = wn * 64 + j * 16 + cc;
        smem[lr * 128 + lc] = bf16_rn(acc[i][j][r] + b2[(size_t)e * DDIM + col0 + lc]);
      }
  __syncthreads();
#pragma unroll
  for (int it = 0; it < 8; ++it) {
    int idx = it * 256 + tid;               // 0..2047: row=idx>>4, cb=idx&15
    int row = idx >> 4, cb = idx & 15;
    *(bfrag*)(eo + (size_t)(by * 128 + row) * DDIM + col0 + cb * 8) =
        *(const bfrag*)&smem[row * 128 + cb * 8];
  }
}

// ---------------- combine + LN2 + classifier, wave-per-token (bf16 eo) ------------
__launch_bounds__(256)
__global__ void k_combine(const unsigned short* __restrict__ eo,
                          const unsigned short* __restrict__ seqb,
                          const int* __restrict__ slot_of, const float* __restrict__ top_w,
                          const float* __restrict__ g2, const float* __restrict__ b2v,
                          const float* __restrict__ cls_w, const float* __restrict__ cls_b,
                          float* __restrict__ out)
{
  int lane = threadIdx.x & 63;
  int t = blockIdx.x * 4 + (threadIdx.x >> 6);
  int s0 = slot_of[t * 2], s1 = slot_of[t * 2 + 1];
  float w0 = top_w[t * 2], w1 = top_w[t * 2 + 1];
  const unsigned short* p0 = eo + (size_t)s0 * DDIM;
  const unsigned short* p1 = eo + (size_t)s1 * DDIM;
  const unsigned short* sq = seqb + (size_t)t * DDIM;
  float m[12];
  float s = 0.f, s2 = 0.f;
#pragma unroll
  for (int j = 0; j < 12; ++j) {
    int d = lane + 64 * j;
    float v = w0 * bf16_f32(p0[d]) + w1 * bf16_f32(p1[d]) + bf16_f32(sq[d]);
    m[j] = v; s += v; s2 += v * v;
  }
#pragma unroll
  for (int o = 32; o > 0; o >>= 1) { s += __shfl_xor(s, o, 64); s2 += __shfl_xor(s2, o, 64); }
  float mu = s * (1.f / DDIM);
  float rstd = rsqrtf(s2 * (1.f / DDIM) - mu * mu + 1e-5f);
  float l0 = 0.f, l1 = 0.f;
#pragma unroll
  for (int j = 0; j < 12; ++j) {
    int d = lane + 64 * j;
    float y = (m[j] - mu) * rstd * g2[d] + b2v[d];
    l0 += y * cls_w[d * 2];
    l1 += y * cls_w[d * 2 + 1];
  }
#pragma unroll
  for (int o = 32; o > 0; o >>= 1) { l0 += __shfl_xor(l0, o, 64); l1 += __shfl_xor(l1, o, 64); }
  if (lane == 0) {
    out[(size_t)t * 2] = l0 + cls_b[0];
    out[(size_t)t * 2 + 1] = l1 + cls_b[1];
  }
}

extern "C" void kernel_launch(void* const* d_in, const int* in_sizes, int n_in,
                              void* d_out, int out_size, void* d_ws, size_t ws_size,
                              hipStream_t stream) {
  const float* hidden = (const float*)d_in[0];
  const float* proj_w = (const float*)d_in[1];
  const float* proj_b = (const float*)d_in[2];
  const float* ln1_g  = (const float*)d_in[3];
  const float* ln1_b  = (const float*)d_in[4];
  const float* gate_w = (const float*)d_in[5];
  const float* gate_b = (const float*)d_in[6];
  const float* w1     = (const float*)d_in[7];
  const float* b1     = (const float*)d_in[8];
  const float* w2     = (const float*)d_in[9];
  const float* b2     = (const float*)d_in[10];
  const float* ln2_g  = (const float*)d_in[11];
  const float* ln2_b  = (const float*)d_in[12];
  const float* cls_w  = (const float*)d_in[13];
  const float* cls_b  = (const float*)d_in[14];
  float* out = (float*)d_out;

  char* base = (char*)d_ws;
  size_t off = 0;
  auto alloc = [&](size_t b) -> void* {
    void* p = base + off;
    off += (b + 255) & ~(size_t)255;
    return p;
  };
  unsigned short* pwT_hi = (unsigned short*)alloc((size_t)DDIM * CDIM * 2);   // tiled
  unsigned short* pwT_lo = (unsigned short*)alloc((size_t)DDIM * CDIM * 2);   // tiled
  unsigned short* w1T    = (unsigned short*)alloc((size_t)NEXP * HDIM * DDIM * 2);  // tiled
  unsigned short* w2T    = (unsigned short*)alloc((size_t)NEXP * DDIM * HDIM * 2);  // tiled
  float* xw              = (float*)alloc((size_t)T_TOK * DDIM * 4);
  float* xw_fix4         = (float*)alloc((size_t)KSPLIT * AMB_CAP * DDIM * 4);
  double* xpart          = (double*)alloc((size_t)NSEG * AMB2_CAP * DDIM * 8);
  unsigned short* seqb   = (unsigned short*)alloc((size_t)T_TOK * DDIM * 2);
  int* top_i             = (int*)alloc((size_t)T_TOK * 2 * 4);
  float* top_w           = (float*)alloc((size_t)T_TOK * 2 * 4);
  int* slot_of           = (int*)alloc((size_t)T_TOK * 2 * 4);
  int* amb_list          = (int*)alloc((size_t)AMB_CAP * 4);
  int* amb2_list         = (int*)alloc((size_t)AMB2_CAP * 4);
  int* token_list        = (int*)alloc((size_t)NSLOT * 4);
  int* counts            = (int*)alloc(256);
  int* cursors           = (int*)alloc(512);
  int* seg_start         = (int*)alloc(256);
  int* padded_total      = (int*)alloc(256);
  int* tile_expert       = (int*)alloc((size_t)MAXTILE * 4);
  unsigned short* zero_row = (unsigned short*)alloc(2048);
  int* amb_count         = (int*)alloc(256);
  int* amb2_count        = (int*)alloc(256);
  unsigned short* hbufT  = (unsigned short*)alloc((size_t)MAXTILE * 32 * 4096 * 2);
  unsigned short* eo     = (unsigned short*)alloc((size_t)NSLOT * DDIM * 2);
  (void)ws_size; (void)in_sizes; (void)n_in; (void)out_size;

  k_init<<<64, 256, 0, stream>>>(token_list, counts, cursors, zero_row, amb_count, amb2_count);
  k_transpose_split<<<dim3(12, 24), 256, 0, stream>>>(proj_w, pwT_hi, pwT_lo);
  k_transpose_tiled<<<dim3(16, 6, 8), 256, 0, stream>>>(w1, w1T, DDIM, HDIM);
  k_transpose_tiled<<<dim3(12, 8, 8), 256, 0, stream>>>(w2, w2T, HDIM, DDIM);
  k_gemm1<<<768, 256, 0, stream>>>(hidden, pwT_hi, xw);
  k_ln_router<<<T_TOK / 4, 256, 0, stream>>>(xw, proj_b, ln1_g, ln1_b, gate_w, gate_b,
                                             seqb, top_i, top_w, amb_list, amb_count);
  k_repair<<<dim3(6, AMB_CAP / 128, KSPLIT), 256, 0, stream>>>(hidden, pwT_hi, pwT_lo,
                                                               amb_list, amb_count, xw_fix4);
  k_fix2<<<AMB_CAP / 4, 256, 0, stream>>>(xw_fix4, proj_b, ln1_g, ln1_b, gate_w, gate_b,
                                          amb_list, amb_count, top_i, top_w,
                                          amb2_list, amb2_count);
  k_router_fix<<<dim3(64, NSEG), 256, 0, stream>>>(hidden, proj_w, amb2_list, amb2_count, xpart);
  k_fix3<<<AMB2_CAP, 256, 0, stream>>>(xpart, proj_b, ln1_g, ln1_b, gate_w, gate_b,
                                       amb2_list, amb2_count, top_i, top_w);
  k_count<<<64, 256, 0, stream>>>(top_i, counts);
  k_offsets<<<1, 64, 0, stream>>>(counts, seg_start, padded_total, tile_expert);
  k_scatter<<<64, 256, 0, stream>>>(top_i, seg_start, cursors, token_list, slot_of);
  k_gemm2<<<MAXTILE * 8, 256, 0, stream>>>(seqb, w1T, b1, token_list, zero_row,
                                           tile_expert, padded_total, hbufT);
  k_gemm3<<<MAXTILE * 6, 256, 0, stream>>>(hbufT, w2T, b2, tile_expert, padded_total, eo);
  k_combine<<<T_TOK / 4, 256, 0, stream>>>(eo, seqb, slot_of, top_w, ln2_g, ln2_b,
                                           cls_w, cls_b, out);
}

// Round 24
// 554.922 us; speedup vs baseline: 1.0090x; 1.0090x over previous
//
#include <hip/hip_runtime.h>
#include <hip/hip_bf16.h>

#define T_TOK 16384
#define CDIM 3072
#define DDIM 768
#define HDIM 1024
#define NEXP 8
#define NSLOT 33792   // 32768 assignments + 8*128 padding
#define MAXTILE 264   // NSLOT/128
#define AMB_CAP 2048  // repair capacity (n ~1100, deterministic for fixed inputs)
#define AMB2_CAP 256  // f64 stage capacity (n2 ~27)
#define KSPLIT 4
#define NSEG 8

typedef __attribute__((ext_vector_type(8))) short bfrag;
typedef __attribute__((ext_vector_type(4))) float f32x4;
typedef __attribute__((ext_vector_type(4))) float fvec4;

__device__ __forceinline__ unsigned short bf16_rn(float f) {
  union { float f; unsigned u; } v; v.f = f;
  unsigned r = v.u + 0x7fffu + ((v.u >> 16) & 1u);
  return (unsigned short)(r >> 16);
}
__device__ __forceinline__ float bf16_f32(unsigned short h) {
  union { unsigned u; float f; } v; v.u = ((unsigned)h) << 16;
  return v.f;
}
__device__ __forceinline__ float gelu_exact(float x) {
  return 0.5f * x * (1.0f + erff(x * 0.70710678118654752440f));
}
__device__ __forceinline__ void glds16(const void* g, void* l) {
  __builtin_amdgcn_global_load_lds((const __attribute__((address_space(1))) void*)g,
                                   (__attribute__((address_space(3))) void*)l, 16, 0, 0);
}

// ---------------- init ----------------
__global__ void k_init(int* token_list, int* counts, int* cursors, unsigned short* zero_row,
                       int* amb_count, int* amb2_count) {
  int i = blockIdx.x * 256 + threadIdx.x;
  for (int j = i; j < NSLOT; j += 64 * 256) token_list[j] = -1;
  if (i < NEXP) counts[i] = 0;
  if (i < 128) cursors[i] = 0;
  if (i == 0) { *amb_count = 0; *amb2_count = 0; }
  if (i < 1024) zero_row[i] = 0;
}

// ---------------- cast hidden f32 -> bf16, TILED layout -------------------------
__global__ void k_cast_tiled(const float* __restrict__ src,
                             unsigned short* __restrict__ dst) {
  __shared__ unsigned short h[128][136];
  int rb = blockIdx.x;          // row block 0..127
  int cc = blockIdx.y;          // col chunk 0..23 (128 cols each)
  int tid = threadIdx.x;
  const float* in = src + ((size_t)rb * 128) * CDIM + cc * 128;
#pragma unroll
  for (int it = 0; it < 16; ++it) {
    int idx = it * 256 + tid;          // 4096 fvec4
    int r = idx >> 5, nv = idx & 31;
    fvec4 v = *(const fvec4*)(in + (size_t)r * CDIM + nv * 4);
    unsigned long long p = (unsigned long long)bf16_rn(v[0]) |
                           ((unsigned long long)bf16_rn(v[1]) << 16) |
                           ((unsigned long long)bf16_rn(v[2]) << 32) |
                           ((unsigned long long)bf16_rn(v[3]) << 48);
    *(unsigned long long*)&h[r][nv * 4] = p;
  }
  __syncthreads();
  unsigned short* ob = dst + ((size_t)rb * 96 + cc * 4) * 4096;
#pragma unroll
  for (int kt = 0; kt < 4; ++kt) {
#pragma unroll
    for (int it = 0; it < 2; ++it) {
      int gg = it * 256 + tid;
      int kg = gg >> 7, r = gg & 127;
      bfrag o = *(const bfrag*)&h[r][kt * 32 + kg * 8];
      *(bfrag*)(ob + ((size_t)kt * 512 + gg) * 8) = o;
    }
  }
}

// ---------------- transpose proj_w -> hi/lo bf16, TILED layout ------------------
__global__ void k_transpose_split(const float* __restrict__ src,   // proj_w [3072][768]
                                  unsigned short* __restrict__ dhi,
                                  unsigned short* __restrict__ dlo) {
  __shared__ unsigned short h[128][72], l[128][72];   // [c_local][n_local]
  int nb2 = blockIdx.x;          // 0..11 : col_blk = nb2>>1, n-half = nb2&1
  int cb = blockIdx.y;           // 0..23 : c0 = cb*128
  int col_blk = nb2 >> 1, nhalf = nb2 & 1;
  int n0 = col_blk * 128 + nhalf * 64;
  int tid = threadIdx.x;
  const float* in = src + (size_t)(cb * 128) * DDIM + n0;
#pragma unroll
  for (int it = 0; it < 8; ++it) {
    int idx = it * 256 + tid;          // 2048 fvec4 (128c x 16 v4)
    int cl = idx >> 4, nv = idx & 15;
    fvec4 v = *(const fvec4*)(in + (size_t)cl * DDIM + nv * 4);
    unsigned long long ph = 0, pl = 0;
#pragma unroll
    for (int e = 0; e < 4; ++e) {
      unsigned short hh = bf16_rn(v[e]);
      unsigned short ll = bf16_rn(v[e] - bf16_f32(hh));
      ph |= (unsigned long long)hh << (16 * e);
      pl |= (unsigned long long)ll << (16 * e);
    }
    *(unsigned long long*)&h[cl][nv * 4] = ph;
    *(unsigned long long*)&l[cl][nv * 4] = pl;
  }
  __syncthreads();
  size_t obase = ((size_t)col_blk * 96 + cb * 4) * 4096;
#pragma unroll
  for (int kt = 0; kt < 4; ++kt) {
    int kg = tid >> 6, rl = tid & 63;
    bfrag oh, ol;
#pragma unroll
    for (int e = 0; e < 8; ++e) {
      int c = kt * 32 + kg * 8 + e;
      oh[e] = (short)h[c][rl];
      ol[e] = (short)l[c][rl];
    }
    size_t gi = obase + ((size_t)kt * 512 + kg * 128 + nhalf * 64 + rl) * 8;
    *(bfrag*)(dhi + gi) = oh;
    *(bfrag*)(dlo + gi) = ol;
  }
}

// ---------------- transpose+cast f32 [z][K][N] -> granule-TILED bf16 ------------
__global__ void k_transpose_tiled(const float* __restrict__ src0,
                                  unsigned short* __restrict__ dst0, int K, int N) {
  __shared__ unsigned short h[128][72];
  int nb2 = blockIdx.x;          // 0..N/64-1
  int cb = blockIdx.y;           // 0..K/128-1
  int z = blockIdx.z;
  int col_blk = nb2 >> 1, nhalf = nb2 & 1;
  int n0 = col_blk * 128 + nhalf * 64;
  int tid = threadIdx.x;
  const float* in = src0 + (size_t)z * K * N + (size_t)(cb * 128) * N + n0;
#pragma unroll
  for (int it = 0; it < 8; ++it) {
    int idx = it * 256 + tid;
    int cl = idx >> 4, nv = idx & 15;
    fvec4 v = *(const fvec4*)(in + (size_t)cl * N + nv * 4);
    unsigned long long ph = 0;
#pragma unroll
    for (int e = 0; e < 4; ++e)
      ph |= (unsigned long long)bf16_rn(v[e]) << (16 * e);
    *(unsigned long long*)&h[cl][nv * 4] = ph;
  }
  __syncthreads();
  size_t obase = (size_t)z * K * N + ((size_t)col_blk * (K / 32) + cb * 4) * 4096;
#pragma unroll
  for (int kt = 0; kt < 4; ++kt) {
    int kg = tid >> 6, rl = tid & 63;
    bfrag oh;
#pragma unroll
    for (int e = 0; e < 8; ++e) oh[e] = (short)h[kt * 32 + kg * 8 + e][rl];
    *(bfrag*)(dst0 + obase + ((size_t)kt * 512 + kg * 128 + nhalf * 64 + rl) * 8) = oh;
  }
}

// ---------------- GEMM1: tiled operands, 3-buffer pipeline, counted vmcnt -------
__launch_bounds__(256, 3)
__global__ void k_gemm1(const unsigned short* __restrict__ Atil,  // [128][96] tiles
                        const unsigned short* __restrict__ Btil,  // [6][96] tiles
                        float* __restrict__ Cout)                 // xw [T][768]
{
  __shared__ unsigned short sA[12288], sB[12288];
  int tid = threadIdx.x;
  int lane = tid & 63, wave = tid >> 6;
  int id = blockIdx.x;                       // 768 blocks
  int swz = (id & 7) * 96 + (id >> 3);       // bijective XCD swizzle
  int brow = swz / 6, bcol = swz % 6;
  int row0 = brow * 128, col0 = bcol * 128;
  int wm = wave >> 1, wn = wave & 1;

  f32x4 acc[4][4];
#pragma unroll
  for (int i = 0; i < 4; ++i)
#pragma unroll
    for (int j = 0; j < 4; ++j) acc[i][j] = (f32x4){0.f, 0.f, 0.f, 0.f};

  int rsel = lane & 15, kq = lane >> 4;
  const unsigned short* At = Atil + (size_t)(brow * 96) * 4096;
  const unsigned short* Bt = Btil + (size_t)(bcol * 96) * 4096;

  auto STAGE = [&](int kt, int b) {
    const unsigned short* as = At + (size_t)kt * 4096;
    const unsigned short* bs = Bt + (size_t)kt * 4096;
    int lbase = b * 4096;
#pragma unroll
    for (int pass = 0; pass < 2; ++pass) {
      int g = pass * 256 + tid;
      int li = lbase + (pass * 256 + wave * 64) * 8;
      glds16(as + (size_t)g * 8, &sA[li]);
      glds16(bs + (size_t)g * 8, &sB[li]);
    }
  };

  STAGE(0, 0);
  STAGE(1, 1);
  int b0 = 0;
  for (int kt = 0; kt < 96; ++kt) {
    if (kt < 95) asm volatile("s_waitcnt vmcnt(4)" ::: "memory");
    else         asm volatile("s_waitcnt vmcnt(0)" ::: "memory");
    __builtin_amdgcn_s_barrier();
    if (kt + 2 < 96) {
      int bn = b0 + 2; if (bn >= 3) bn -= 3;
      STAGE(kt + 2, bn);
    }
    int lb = b0 * 4096;
    bfrag af[4], bf[4];
#pragma unroll
    for (int i = 0; i < 4; ++i) {
      af[i] = *(const bfrag*)&sA[lb + (kq * 128 + wm * 64 + i * 16 + rsel) * 8];
      bf[i] = *(const bfrag*)&sB[lb + (kq * 128 + wn * 64 + i * 16 + rsel) * 8];
    }
#pragma unroll
    for (int i = 0; i < 4; ++i)
#pragma unroll
      for (int j = 0; j < 4; ++j)
        acc[i][j] = __builtin_amdgcn_mfma_f32_16x16x32_bf16(af[i], bf[j], acc[i][j], 0, 0, 0);
    b0 = (b0 == 2) ? 0 : b0 + 1;
  }

  int cc = lane & 15, rr = (lane >> 4) * 4;
#pragma unroll
  for (int i = 0; i < 4; ++i)
#pragma unroll
    for (int j = 0; j < 4; ++j)
#pragma unroll
      for (int r = 0; r < 4; ++r) {
        int row = row0 + wm * 64 + i * 16 + rr + r;
        int col = col0 + wn * 64 + j * 16 + cc;
        Cout[(size_t)row * DDIM + col] = acc[i][j][r];
      }
}

// ---------------- LN1 + GELU + router, wave-per-token (flag gap23 < 8e-3) ----------
__launch_bounds__(256)
__global__ void k_ln_router(const float* __restrict__ xw, const float* __restrict__ proj_b,
                            const float* __restrict__ g1, const float* __restrict__ b1v,
                            const float* __restrict__ gate_w, const float* __restrict__ gate_b,
                            unsigned short* __restrict__ seq_b16,
                            int* __restrict__ top_i, float* __restrict__ top_w,
                            int* __restrict__ amb_list, int* __restrict__ amb_count)
{
  int lane = threadIdx.x & 63;
  int t = blockIdx.x * 4 + (threadIdx.x >> 6);
  const float* xr = xw + (size_t)t * DDIM;
  float x0[12];
  float s = 0.f, s2 = 0.f;
#pragma unroll
  for (int j = 0; j < 12; ++j) {
    int d = lane + 64 * j;
    float v = xr[d] + proj_b[d];
    x0[j] = v; s += v; s2 += v * v;
  }
#pragma unroll
  for (int o = 32; o > 0; o >>= 1) { s += __shfl_xor(s, o, 64); s2 += __shfl_xor(s2, o, 64); }
  float mu = s * (1.f / DDIM);
  float rstd = rsqrtf(s2 * (1.f / DDIM) - mu * mu + 1e-5f);
  float acc8[8];
#pragma unroll
  for (int e = 0; e < 8; ++e) acc8[e] = 0.f;
#pragma unroll
  for (int j = 0; j < 12; ++j) {
    int d = lane + 64 * j;
    float y = (x0[j] - mu) * rstd * g1[d] + b1v[d];
    float ge = gelu_exact(y);
    seq_b16[(size_t)t * DDIM + d] = bf16_rn(ge);
    const float* gw = gate_w + (size_t)d * NEXP;
#pragma unroll
    for (int e = 0; e < 8; ++e) acc8[e] += ge * gw[e];
  }
#pragma unroll
  for (int e = 0; e < 8; ++e)
#pragma unroll
    for (int o = 32; o > 0; o >>= 1) acc8[e] += __shfl_xor(acc8[e], o, 64);
  if (lane == 0) {
    float lg[8];
#pragma unroll
    for (int e = 0; e < 8; ++e) lg[e] = acc8[e] + gate_b[e];
    int i0 = 0;
    for (int e = 1; e < 8; ++e) if (lg[e] > lg[i0]) i0 = e;
    int i1 = (i0 == 0) ? 1 : 0;
    for (int e = 0; e < 8; ++e) if (e != i0 && lg[e] > lg[i1]) i1 = e;
    float l2 = -1e30f;
    for (int e = 0; e < 8; ++e) if (e != i0 && e != i1 && lg[e] > l2) l2 = lg[e];
    if (lg[i1] - l2 < 8e-3f) {
      int p = atomicAdd(amb_count, 1);
      if (p < AMB_CAP) amb_list[p] = t;
    }
    float w0 = 1.f / (1.f + expf(lg[i1] - lg[i0]));
    top_i[t * 2] = i0; top_i[t * 2 + 1] = i1;
    top_w[t * 2] = w0; top_w[t * 2 + 1] = 1.f - w0;
  }
}

// ---------------- repair GEMM: 3-term split-bf16, K-split x4, 2-phase dbuf ---------
__launch_bounds__(256, 2)
__global__ void k_repair(const float* __restrict__ hidden,
                         const unsigned short* __restrict__ BTh,   // tiled [6][96]
                         const unsigned short* __restrict__ BTl,
                         const int* __restrict__ amb_list, const int* __restrict__ amb_count,
                         float* __restrict__ xw_fix4)   // [KSPLIT][AMB_CAP][768]
{
  int n = *amb_count; if (n > AMB_CAP) n = AMB_CAP;
  int by = blockIdx.y;
  if (by * 128 >= n) return;
  int bx = blockIdx.x;                 // 0..5
  int z = blockIdx.z;                  // 0..3 K-quarter
  int col0 = bx * 128;
  __shared__ unsigned short sAh[8192], sAl[8192], sBh[8192], sBl[8192];
  __shared__ int tk[128];
  int tid = threadIdx.x, lane = tid & 63, wave = tid >> 6;
  if (tid < 128) tk[tid] = (by * 128 + tid < n) ? amb_list[by * 128 + tid] : -1;
  __syncthreads();
  int wm = wave >> 1, wn = wave & 1;
  f32x4 acc[4][4];
#pragma unroll
  for (int i = 0; i < 4; ++i)
#pragma unroll
    for (int j = 0; j < 4; ++j) acc[i][j] = (f32x4){0.f, 0.f, 0.f, 0.f};
  int rsel = lane & 15, kq = lane >> 4;
  int ktbase = z * 24;
  const unsigned short* Bth = BTh + (size_t)(bx * 96) * 4096;
  const unsigned short* Btl = BTl + (size_t)(bx * 96) * 4096;

  auto STAGE = [&](int kt, int b) {
    int k0 = (ktbase + kt) * 32;
    int lb = b * 4096;
    size_t tb = (size_t)(ktbase + kt) * 4096;
#pragma unroll
    for (int pass = 0; pass < 2; ++pass) {
      int g = pass * 256 + tid;
      int kg = g >> 7, r = g & 127;
      int tok = tk[r];
      fvec4 a0 = (fvec4){0.f, 0.f, 0.f, 0.f}, a1 = a0;
      if (tok >= 0) {
        const float* ap = hidden + (size_t)tok * CDIM + k0 + kg * 8;
        a0 = *(const fvec4*)ap;
        a1 = *(const fvec4*)(ap + 4);
      }
      bfrag hv, lv;
#pragma unroll
      for (int u = 0; u < 8; ++u) {
        float v = (u < 4) ? a0[u] : a1[u - 4];
        unsigned short h = bf16_rn(v);
        hv[u] = (short)h;
        lv[u] = (short)bf16_rn(v - bf16_f32(h));
      }
      *(bfrag*)&sAh[lb + (size_t)g * 8] = hv;
      *(bfrag*)&sAl[lb + (size_t)g * 8] = lv;
      int li = lb + (pass * 256 + wave * 64) * 8;
      glds16(Bth + tb + (size_t)g * 8, &sBh[li]);
      glds16(Btl + tb + (size_t)g * 8, &sBl[li]);
    }
  };

  STAGE(0, 0);
  __syncthreads();
  for (int kt = 0; kt < 24; ++kt) {
    int b = kt & 1;
    if (kt + 1 < 24) STAGE(kt + 1, b ^ 1);
    int lb = b * 4096;
    bfrag ah[4], al[4], bh[4], bl[4];
#pragma unroll
    for (int i = 0; i < 4; ++i) {
      int ra = wm * 64 + i * 16 + rsel;
      ah[i] = *(const bfrag*)&sAh[lb + (kq * 128 + ra) * 8];
      al[i] = *(const bfrag*)&sAl[lb + (kq * 128 + ra) * 8];
      int cb = wn * 64 + i * 16 + rsel;
      bh[i] = *(const bfrag*)&sBh[lb + (kq * 128 + cb) * 8];
      bl[i] = *(const bfrag*)&sBl[lb + (kq * 128 + cb) * 8];
    }
#pragma unroll
    for (int i = 0; i < 4; ++i)
#pragma unroll
      for (int j = 0; j < 4; ++j) {
        acc[i][j] = __builtin_amdgcn_mfma_f32_16x16x32_bf16(ah[i], bh[j], acc[i][j], 0, 0, 0);
        acc[i][j] = __builtin_amdgcn_mfma_f32_16x16x32_bf16(ah[i], bl[j], acc[i][j], 0, 0, 0);
        acc[i][j] = __builtin_amdgcn_mfma_f32_16x16x32_bf16(al[i], bh[j], acc[i][j], 0, 0, 0);
      }
    __syncthreads();
  }
  float* dst = xw_fix4 + (size_t)z * AMB_CAP * DDIM;
  int cc = lane & 15, rr = (lane >> 4) * 4;
#pragma unroll
  for (int i = 0; i < 4; ++i)
#pragma unroll
    for (int j = 0; j < 4; ++j)
#pragma unroll
      for (int r = 0; r < 4; ++r) {
        int row = by * 128 + wm * 64 + i * 16 + rr + r;
        int col = col0 + wn * 64 + j * 16 + cc;
        dst[(size_t)row * DDIM + col] = acc[i][j][r];
      }
}

// ---------------- fix2: re-route ambiguous tokens from precise xw_fix4 ------------
__launch_bounds__(256)
__global__ void k_fix2(const float* __restrict__ xw_fix4, const float* __restrict__ proj_b,
                       const float* __restrict__ g1, const float* __restrict__ b1v,
                       const float* __restrict__ gate_w, const float* __restrict__ gate_b,
                       const int* __restrict__ amb_list, const int* __restrict__ amb_count,
                       int* __restrict__ top_i, float* __restrict__ top_w,
                       int* __restrict__ amb2_list, int* __restrict__ amb2_count)
{
  int n = *amb_count; if (n > AMB_CAP) n = AMB_CAP;
  int lane = threadIdx.x & 63;
  int slot = blockIdx.x * 4 + (threadIdx.x >> 6);
  if (slot >= n) return;
  int t = amb_list[slot];
  const float* p0 = xw_fix4 + (size_t)slot * DDIM;
  const float* p1 = p0 + (size_t)AMB_CAP * DDIM;
  const float* p2 = p1 + (size_t)AMB_CAP * DDIM;
  const float* p3 = p2 + (size_t)AMB_CAP * DDIM;
  float x0[12];
  float s = 0.f, s2 = 0.f;
#pragma unroll
  for (int j = 0; j < 12; ++j) {
    int d = lane + 64 * j;
    float v = ((p0[d] + p1[d]) + (p2[d] + p3[d])) + proj_b[d];
    x0[j] = v; s += v; s2 += v * v;
  }
#pragma unroll
  for (int o = 32; o > 0; o >>= 1) { s += __shfl_xor(s, o, 64); s2 += __shfl_xor(s2, o, 64); }
  float mu = s * (1.f / DDIM);
  float rstd = rsqrtf(s2 * (1.f / DDIM) - mu * mu + 1e-5f);
  float acc8[8];
#pragma unroll
  for (int e = 0; e < 8; ++e) acc8[e] = 0.f;
#pragma unroll
  for (int j = 0; j < 12; ++j) {
    int d = lane + 64 * j;
    float y = (x0[j] - mu) * rstd * g1[d] + b1v[d];
    float ge = gelu_exact(y);
    const float* gw = gate_w + (size_t)d * NEXP;
#pragma unroll
    for (int e = 0; e < 8; ++e) acc8[e] += ge * gw[e];
  }
#pragma unroll
  for (int e = 0; e < 8; ++e)
#pragma unroll
    for (int o = 32; o > 0; o >>= 1) acc8[e] += __shfl_xor(acc8[e], o, 64);
  if (lane == 0) {
    float lg[8];
#pragma unroll
    for (int e = 0; e < 8; ++e) lg[e] = acc8[e] + gate_b[e];
    int i0 = 0;
    for (int e = 1; e < 8; ++e) if (lg[e] > lg[i0]) i0 = e;
    int i1 = (i0 == 0) ? 1 : 0;
    for (int e = 0; e < 8; ++e) if (e != i0 && lg[e] > lg[i1]) i1 = e;
    float l2 = -1e30f;
    for (int e = 0; e < 8; ++e) if (e != i0 && e != i1 && lg[e] > l2) l2 = lg[e];
    if (lg[i1] - l2 < 2e-4f) {
      int p = atomicAdd(amb2_count, 1);
      if (p < AMB2_CAP) amb2_list[p] = t;
    }
    float w0 = 1.f / (1.f + expf(lg[i1] - lg[i0]));
    top_i[t * 2] = i0; top_i[t * 2 + 1] = i1;
    top_w[t * 2] = w0; top_w[t * 2 + 1] = 1.f - w0;
  }
}

// ---------------- f64 proj partials, C-split x8 ----------------
__launch_bounds__(256, 1)
__global__ void k_router_fix(const float* __restrict__ hidden, const float* __restrict__ proj_w,
                             const int* __restrict__ amb2_list, const int* __restrict__ amb2_count,
                             double* __restrict__ xpart)   // [NSEG][AMB2_CAP][768]
{
  __shared__ float hrow[384];
  int tid = threadIdx.x;
  int seg = blockIdx.y;
  int cbase = seg * 384;
  int n = *amb2_count; if (n > AMB2_CAP) n = AMB2_CAP;
  for (int ii = blockIdx.x; ii < n; ii += gridDim.x) {
    int t = amb2_list[ii];
    __syncthreads();
    if (tid < 96)
      *(fvec4*)&hrow[tid * 4] = *(const fvec4*)(hidden + (size_t)t * CDIM + cbase + tid * 4);
    __syncthreads();
    double p0a = 0.0, p0b = 0.0, p1a = 0.0, p1b = 0.0, p2a = 0.0, p2b = 0.0;
    for (int c0 = 0; c0 < 384; c0 += 16) {
      float w0r[16], w1r[16], w2r[16];
      const float* wp = proj_w + (size_t)(cbase + c0) * DDIM + tid;
#pragma unroll
      for (int u = 0; u < 16; ++u) {
        w0r[u] = wp[u * DDIM];
        w1r[u] = wp[u * DDIM + 256];
        w2r[u] = wp[u * DDIM + 512];
      }
#pragma unroll
      for (int u = 0; u < 16; ++u) {
        double h = (double)hrow[c0 + u];
        if (u & 1) { p0b += h * (double)w0r[u]; p1b += h * (double)w1r[u]; p2b += h * (double)w2r[u]; }
        else       { p0a += h * (double)w0r[u]; p1a += h * (double)w1r[u]; p2a += h * (double)w2r[u]; }
      }
    }
    double* xp = xpart + ((size_t)seg * AMB2_CAP + ii) * DDIM;
    xp[tid] = p0a + p0b;
    xp[tid + 256] = p1a + p1b;
    xp[tid + 512] = p2a + p2b;
  }
}

// ---------------- fix3: combine f64 partials, LN + gelu + gate in f64 ------------
__launch_bounds__(256)
__global__ void k_fix3(const double* __restrict__ xpart, const float* __restrict__ proj_b,
                       const float* __restrict__ g1, const float* __restrict__ b1v,
                       const float* __restrict__ gate_w, const float* __restrict__ gate_b,
                       const int* __restrict__ amb2_list, const int* __restrict__ amb2_count,
                       int* __restrict__ top_i, float* __restrict__ top_w)
{
  __shared__ double redA[4], redB[4], red8[4][8];
  int n = *amb2_count; if (n > AMB2_CAP) n = AMB2_CAP;
  int ii = blockIdx.x;
  if (ii >= n) return;
  int t = amb2_list[ii];
  int tid = threadIdx.x, lane = tid & 63, wave = tid >> 6;
  double x[3]; double s = 0.0, s2 = 0.0;
#pragma unroll
  for (int j = 0; j < 3; ++j) {
    int d = tid + 256 * j;
    double acc = (double)proj_b[d];
#pragma unroll
    for (int seg = 0; seg < NSEG; ++seg)
      acc += xpart[((size_t)seg * AMB2_CAP + ii) * DDIM + d];
    x[j] = acc; s += acc; s2 += acc * acc;
  }
#pragma unroll
  for (int o = 32; o > 0; o >>= 1) { s += __shfl_down(s, o, 64); s2 += __shfl_down(s2, o, 64); }
  if (lane == 0) { redA[wave] = s; redB[wave] = s2; }
  __syncthreads();
  double mu = (redA[0] + redA[1] + redA[2] + redA[3]) / DDIM;
  double ms = (redB[0] + redB[1] + redB[2] + redB[3]) / DDIM;
  double rstd = 1.0 / sqrt(ms - mu * mu + 1e-5);
  double a8[8];
#pragma unroll
  for (int e = 0; e < 8; ++e) a8[e] = 0.0;
#pragma unroll
  for (int j = 0; j < 3; ++j) {
    int d = tid + 256 * j;
    double y = (x[j] - mu) * rstd * (double)g1[d] + (double)b1v[d];
    double ge = 0.5 * y * (1.0 + erf(y * 0.7071067811865475244));
#pragma unroll
    for (int e = 0; e < 8; ++e) a8[e] += ge * (double)gate_w[(size_t)d * NEXP + e];
  }
#pragma unroll
  for (int e = 0; e < 8; ++e)
#pragma unroll
    for (int o = 32; o > 0; o >>= 1) a8[e] += __shfl_down(a8[e], o, 64);
  if (lane == 0) {
#pragma unroll
    for (int e = 0; e < 8; ++e) red8[wave][e] = a8[e];
  }
  __syncthreads();
  if (tid == 0) {
    double lg[8];
#pragma unroll
    for (int e = 0; e < 8; ++e)
      lg[e] = red8[0][e] + red8[1][e] + red8[2][e] + red8[3][e] + (double)gate_b[e];
    int i0 = 0;
    for (int e = 1; e < 8; ++e) if (lg[e] > lg[i0]) i0 = e;
    int i1 = (i0 == 0) ? 1 : 0;
    for (int e = 0; e < 8; ++e) if (e != i0 && e != i1 && lg[e] > lg[i1]) i1 = e;
    double w0 = 1.0 / (1.0 + exp(lg[i1] - lg[i0]));
    top_i[t * 2] = i0; top_i[t * 2 + 1] = i1;
    top_w[t * 2] = (float)w0; top_w[t * 2 + 1] = (float)(1.0 - w0);
  }
}

// ---------------- histogram of final top_i (LDS privatized) ----------------
__global__ void k_count(const int* __restrict__ top_i, int* __restrict__ counts) {
  __shared__ int h[NEXP];
  int tid = threadIdx.x;
  if (tid < NEXP) h[tid] = 0;
  __syncthreads();
  for (int i = blockIdx.x * 256 + tid; i < 2 * T_TOK; i += 64 * 256)
    atomicAdd(&h[top_i[i]], 1);
  __syncthreads();
  if (tid < NEXP) atomicAdd(&counts[tid], h[tid]);
}

// ---------------- offsets (single thread) ----------------
__global__ void k_offsets(const int* __restrict__ counts, int* __restrict__ seg_start,
                          int* __restrict__ padded_total, int* __restrict__ tile_expert) {
  if (threadIdx.x != 0 || blockIdx.x != 0) return;
  int st[NEXP], en[NEXP];
  int s = 0;
  for (int e = 0; e < NEXP; ++e) {
    st[e] = s; seg_start[e] = s;
    s += (counts[e] + 127) & ~127;
    en[e] = s;
  }
  *padded_total = s;
  int nt = s >> 7;
  for (int x = 0; x < nt; ++x) {
    int r = x << 7, e = 0;
    for (int q = 0; q < NEXP; ++q) if (r >= st[q] && r < en[q]) e = q;
    tile_expert[x] = e;
  }
}

// ---------------- scatter: block-aggregated cursors ----------------
__global__ void k_scatter(const int* __restrict__ top_i, const int* __restrict__ seg_start,
                          int* __restrict__ cursors, int* __restrict__ token_list,
                          int* __restrict__ slot_of) {
  __shared__ int lc[NEXP];
  __shared__ int lbase[NEXP];
  int tid = threadIdx.x;
  int t = blockIdx.x * 256 + tid;
  if (tid < NEXP) lc[tid] = 0;
  __syncthreads();
  int e0 = top_i[t * 2], e1 = top_i[t * 2 + 1];
  int o0 = atomicAdd(&lc[e0], 1);
  int o1 = atomicAdd(&lc[e1], 1);
  __syncthreads();
  if (tid < NEXP) lbase[tid] = atomicAdd(&cursors[tid << 4], lc[tid]);
  __syncthreads();
  int p0 = seg_start[e0] + lbase[e0] + o0;
  int p1 = seg_start[e1] + lbase[e1] + o1;
  token_list[p0] = t;
  token_list[p1] = t;
  slot_of[t * 2] = p0;
  slot_of[t * 2 + 1] = p1;
}

// ---------------- GEMM2: 128x128, 3-buf, fused gather (per-lane glds16 src) ------
__launch_bounds__(256, 3)
__global__ void k_gemm2(const unsigned short* __restrict__ seqb,   // [T][768] bf16
                        const unsigned short* __restrict__ w1T,    // tiled [E][8][24]
                        const float* __restrict__ b1,              // [E][1024]
                        const int* __restrict__ token_list,
                        const unsigned short* __restrict__ zero_row,
                        const int* __restrict__ tile_expert,
                        const int* __restrict__ padded_total,
                        unsigned short* __restrict__ hbufT)        // tiled [264][32]
{
  // 1-D grid 264*8. XCD slab + bx innermost: 8 consecutive blocks on one XCD
  // share the same A rows (seqb stays in L2), B panel cycles inside.
  int oid = blockIdx.x;                   // 0..2111
  int xcd = oid & 7, w = oid >> 3;        // w: 0..263
  int by = xcd * 33 + (w >> 3);           // 33 tiles per XCD slab
  int bx = w & 7;                         // 0..7 innermost
  if (by * 128 >= *padded_total) return;
  int e = tile_expert[by];
  __shared__ unsigned short smem[24576];  // sA 3x4096, sB 3x4096 (48 KB)
  unsigned short* sA = smem;
  unsigned short* sB = smem + 12288;
  int tid = threadIdx.x, lane = tid & 63, wave = tid >> 6;
  int col0 = bx * 128;
  int wm = wave >> 1, wn = wave & 1;
  f32x4 acc[4][4];
#pragma unroll
  for (int i = 0; i < 4; ++i)
#pragma unroll
    for (int j = 0; j < 4; ++j) acc[i][j] = (f32x4){0.f, 0.f, 0.f, 0.f};
  // fused gather: this thread always stages row r = tid&127 of the A tile.
  int tokreg = token_list[by * 128 + (tid & 127)];
  const unsigned short* a0;  // pass-0 source base (kg = tid>>7)
  const unsigned short* a1;  // pass-1 source base (kg = 2 + (tid>>7))
  int astep;
  if (tokreg >= 0) {
    a0 = seqb + (size_t)tokreg * DDIM + (tid >> 7) * 8;
    a1 = a0 + 16;
    astep = 32;                  // bf16 elems per K-tile along the row
  } else {
    a0 = zero_row + (tid >> 7) * 8;
    a1 = a0 + 16;
    astep = 0;
  }
  const unsigned short* Bt = w1T + (size_t)e * HDIM * DDIM + (size_t)bx * 24 * 4096;
  int rsel = lane & 15, kq = lane >> 4;

  auto STAGE = [&](int kt, int b) {
    int lbase2 = b * 4096;
    size_t tb = (size_t)kt * 4096;
    glds16(a0 + (size_t)kt * astep, &sA[lbase2 + (wave * 64) * 8]);
    glds16(Bt + tb + (size_t)tid * 8, &sB[lbase2 + (wave * 64) * 8]);
    glds16(a1 + (size_t)kt * astep, &sA[lbase2 + (256 + wave * 64) * 8]);
    glds16(Bt + tb + (size_t)(256 + tid) * 8, &sB[lbase2 + (256 + wave * 64) * 8]);
  };

  STAGE(0, 0);
  STAGE(1, 1);
  int b0 = 0;
  for (int kt = 0; kt < 24; ++kt) {
    if (kt < 23) asm volatile("s_waitcnt vmcnt(4)" ::: "memory");
    else         asm volatile("s_waitcnt vmcnt(0)" ::: "memory");
    __builtin_amdgcn_s_barrier();
    if (kt + 2 < 24) {
      int bn = b0 + 2; if (bn >= 3) bn -= 3;
      STAGE(kt + 2, bn);
    }
    int lb = b0 * 4096;
    bfrag af[4], bf[4];
#pragma unroll
    for (int i = 0; i < 4; ++i) {
      af[i] = *(const bfrag*)&sA[lb + (kq * 128 + wm * 64 + i * 16 + rsel) * 8];
      bf[i] = *(const bfrag*)&sB[lb + (kq * 128 + wn * 64 + i * 16 + rsel) * 8];
    }
#pragma unroll
    for (int i = 0; i < 4; ++i)
#pragma unroll
      for (int j = 0; j < 4; ++j)
        acc[i][j] = __builtin_amdgcn_mfma_f32_16x16x32_bf16(af[i], bf[j], acc[i][j], 0, 0, 0);
    b0 = (b0 == 2) ? 0 : b0 + 1;
  }
  // epilogue: stage 128x128 bf16 into LDS granule-linear, then linear 32KB copy.
  __builtin_amdgcn_s_barrier();   // all MFMA reads of smem done
  int cc = lane & 15, rr = (lane >> 4) * 4;
#pragma unroll
  for (int i = 0; i < 4; ++i)
#pragma unroll
    for (int j = 0; j < 4; ++j)
#pragma unroll
      for (int r = 0; r < 4; ++r) {
        int lr = wm * 64 + i * 16 + rr + r;              // local row
        int lc = wn * 64 + j * 16 + cc;                  // local col 0..127
        float x = acc[i][j][r] + b1[(size_t)e * HDIM + col0 + lc];
        int gi = (lc >> 5) * 4096 + ((lc >> 3) & 3) * 1024 + lr * 8 + (lc & 7);
        smem[gi] = bf16_rn(gelu_exact(x));
      }
  __syncthreads();
  unsigned short* dst = hbufT + ((size_t)by * 32 + (col0 >> 5)) * 4096;
#pragma unroll
  for (int it = 0; it < 8; ++it) {
    int idx = it * 256 + tid;                            // bfrag 0..2047
    *(bfrag*)(dst + (size_t)idx * 8) = *(const bfrag*)&smem[idx * 8];
  }
}

// ---------------- GEMM3: 128x128, 3-buf + counted vmcnt, panel-innermost slab ----
__launch_bounds__(256, 3)
__global__ void k_gemm3(const unsigned short* __restrict__ hbufT,  // tiled [264][32]
                        const unsigned short* __restrict__ w2T,    // tiled [E][6][32]
                        const float* __restrict__ b2,              // [E][768]
                        const int* __restrict__ tile_expert,
                        const int* __restrict__ padded_total,
                        unsigned short* __restrict__ eo)           // bf16 [NSLOT][768]
{
  // 1-D grid 264*6. XCD slab + bx innermost (6 consecutive blocks share A tile).
  int oid = blockIdx.x;                   // 0..1583
  int xcd = oid & 7, w = oid >> 3;        // w: 0..197
  int by = xcd * 33 + (w / 6);            // w/6 < 33
  int bx = w % 6;                         // 0..5 innermost
  if (by * 128 >= *padded_total) return;
  int e = tile_expert[by];
  __shared__ unsigned short smem[24576];
  unsigned short* sA = smem;
  unsigned short* sB = smem + 12288;
  int tid = threadIdx.x, lane = tid & 63, wave = tid >> 6;
  int col0 = bx * 128;
  int wm = wave >> 1, wn = wave & 1;
  f32x4 acc[4][4];
#pragma unroll
  for (int i = 0; i < 4; ++i)
#pragma unroll
    for (int j = 0; j < 4; ++j) acc[i][j] = (f32x4){0.f, 0.f, 0.f, 0.f};
  const unsigned short* At = hbufT + (size_t)by * 32 * 4096;
  const unsigned short* Bt = w2T + (size_t)e * DDIM * HDIM + (size_t)bx * 32 * 4096;
  int rsel = lane & 15, kq = lane >> 4;

  auto STAGE = [&](int kt, int b) {
    int lbase2 = b * 4096;
    size_t tb = (size_t)kt * 4096;
#pragma unroll
    for (int pass = 0; pass < 2; ++pass) {
      int g = pass * 256 + tid;
      int li = lbase2 + (pass * 256 + wave * 64) * 8;
      glds16(At + tb + (size_t)g * 8, &sA[li]);
      glds16(Bt + tb + (size_t)g * 8, &sB[li]);
    }
  };

  STAGE(0, 0);
  STAGE(1, 1);
  int b0 = 0;
  for (int kt = 0; kt < 32; ++kt) {
    if (kt < 31) asm volatile("s_waitcnt vmcnt(4)" ::: "memory");
    else         asm volatile("s_waitcnt vmcnt(0)" ::: "memory");
    __builtin_amdgcn_s_barrier();
    if (kt + 2 < 32) {
      int bn = b0 + 2; if (bn >= 3) bn -= 3;
      STAGE(kt + 2, bn);
    }
    int lb = b0 * 4096;
    bfrag af[4], bf[4];
#pragma unroll
    for (int i = 0; i < 4; ++i) {
      af[i] = *(const bfrag*)&sA[lb + (kq * 128 + wm * 64 + i * 16 + rsel) * 8];
      bf[i] = *(const bfrag*)&sB[lb + (kq * 128 + wn * 64 + i * 16 + rsel) * 8];
    }
#pragma unroll
    for (int i = 0; i < 4; ++i)
#pragma unroll
      for (int j = 0; j < 4; ++j)
        acc[i][j] = __builtin_amdgcn_mfma_f32_16x16x32_bf16(af[i], bf[j], acc[i][j], 0, 0, 0);
    b0 = (b0 == 2) ? 0 : b0 + 1;
  }
  // epilogue: stage 128x128 bf16 into LDS row-major, then coalesced row writes.
  __builtin_amdgcn_s_barrier();
  int cc = lane & 15, rr = (lane >> 4) * 4;
#pragma unroll
  for (int i = 0; i < 4; ++i)
#pragma unroll
    for (int j = 0; j < 4; ++j)
#pragma unroll
      for (int r = 0; r < 4; ++r) {
        int lr = wm * 64 + i * 16 + rr + r;
        int lc = wn * 64 + j * 16 + cc;
        smem[lr * 128 + lc] = bf16_rn(acc[i][j][r] + b2[(size_t)e * DDIM + col0 + lc]);
      }
  __syncthreads();
#pragma unroll
  for (int it = 0; it < 8; ++it) {
    int idx = it * 256 + tid;               // 0..2047: row=idx>>4, cb=idx&15
    int row = idx >> 4, cb = idx & 15;
    *(bfrag*)(eo + (size_t)(by * 128 + row) * DDIM + col0 + cb * 8) =
        *(const bfrag*)&smem[row * 128 + cb * 8];
  }
}

// ---------------- combine + LN2 + classifier, wave-per-token (bf16 eo) ------------
__launch_bounds__(256)
__global__ void k_combine(const unsigned short* __restrict__ eo,
                          const unsigned short* __restrict__ seqb,
                          const int* __restrict__ slot_of, const float* __restrict__ top_w,
                          const float* __restrict__ g2, const float* __restrict__ b2v,
                          const float* __restrict__ cls_w, const float* __restrict__ cls_b,
                          float* __restrict__ out)
{
  int lane = threadIdx.x & 63;
  int t = blockIdx.x * 4 + (threadIdx.x >> 6);
  int s0 = slot_of[t * 2], s1 = slot_of[t * 2 + 1];
  float w0 = top_w[t * 2], w1 = top_w[t * 2 + 1];
  const unsigned short* p0 = eo + (size_t)s0 * DDIM;
  const unsigned short* p1 = eo + (size_t)s1 * DDIM;
  const unsigned short* sq = seqb + (size_t)t * DDIM;
  float m[12];
  float s = 0.f, s2 = 0.f;
#pragma unroll
  for (int j = 0; j < 12; ++j) {
    int d = lane + 64 * j;
    float v = w0 * bf16_f32(p0[d]) + w1 * bf16_f32(p1[d]) + bf16_f32(sq[d]);
    m[j] = v; s += v; s2 += v * v;
  }
#pragma unroll
  for (int o = 32; o > 0; o >>= 1) { s += __shfl_xor(s, o, 64); s2 += __shfl_xor(s2, o, 64); }
  float mu = s * (1.f / DDIM);
  float rstd = rsqrtf(s2 * (1.f / DDIM) - mu * mu + 1e-5f);
  float l0 = 0.f, l1 = 0.f;
#pragma unroll
  for (int j = 0; j < 12; ++j) {
    int d = lane + 64 * j;
    float y = (m[j] - mu) * rstd * g2[d] + b2v[d];
    l0 += y * cls_w[d * 2];
    l1 += y * cls_w[d * 2 + 1];
  }
#pragma unroll
  for (int o = 32; o > 0; o >>= 1) { l0 += __shfl_xor(l0, o, 64); l1 += __shfl_xor(l1, o, 64); }
  if (lane == 0) {
    out[(size_t)t * 2] = l0 + cls_b[0];
    out[(size_t)t * 2 + 1] = l1 + cls_b[1];
  }
}

extern "C" void kernel_launch(void* const* d_in, const int* in_sizes, int n_in,
                              void* d_out, int out_size, void* d_ws, size_t ws_size,
                              hipStream_t stream) {
  const float* hidden = (const float*)d_in[0];
  const float* proj_w = (const float*)d_in[1];
  const float* proj_b = (const float*)d_in[2];
  const float* ln1_g  = (const float*)d_in[3];
  const float* ln1_b  = (const float*)d_in[4];
  const float* gate_w = (const float*)d_in[5];
  const float* gate_b = (const float*)d_in[6];
  const float* w1     = (const float*)d_in[7];
  const float* b1     = (const float*)d_in[8];
  const float* w2     = (const float*)d_in[9];
  const float* b2     = (const float*)d_in[10];
  const float* ln2_g  = (const float*)d_in[11];
  const float* ln2_b  = (const float*)d_in[12];
  const float* cls_w  = (const float*)d_in[13];
  const float* cls_b  = (const float*)d_in[14];
  float* out = (float*)d_out;

  char* base = (char*)d_ws;
  size_t off = 0;
  auto alloc = [&](size_t b) -> void* {
    void* p = base + off;
    off += (b + 255) & ~(size_t)255;
    return p;
  };
  unsigned short* pwT_hi = (unsigned short*)alloc((size_t)DDIM * CDIM * 2);   // tiled
  unsigned short* pwT_lo = (unsigned short*)alloc((size_t)DDIM * CDIM * 2);   // tiled
  unsigned short* w1T    = (unsigned short*)alloc((size_t)NEXP * HDIM * DDIM * 2);  // tiled
  unsigned short* w2T    = (unsigned short*)alloc((size_t)NEXP * DDIM * HDIM * 2);  // tiled
  float* xw              = (float*)alloc((size_t)T_TOK * DDIM * 4);
  float* xw_fix4         = (float*)alloc((size_t)KSPLIT * AMB_CAP * DDIM * 4);
  double* xpart          = (double*)alloc((size_t)NSEG * AMB2_CAP * DDIM * 8);
  unsigned short* seqb   = (unsigned short*)alloc((size_t)T_TOK * DDIM * 2);
  int* top_i             = (int*)alloc((size_t)T_TOK * 2 * 4);
  float* top_w           = (float*)alloc((size_t)T_TOK * 2 * 4);
  int* slot_of           = (int*)alloc((size_t)T_TOK * 2 * 4);
  int* amb_list          = (int*)alloc((size_t)AMB_CAP * 4);
  int* amb2_list         = (int*)alloc((size_t)AMB2_CAP * 4);
  int* token_list        = (int*)alloc((size_t)NSLOT * 4);
  int* counts            = (int*)alloc(256);
  int* cursors           = (int*)alloc(512);
  int* seg_start         = (int*)alloc(256);
  int* padded_total      = (int*)alloc(256);
  int* tile_expert       = (int*)alloc((size_t)MAXTILE * 4);
  unsigned short* zero_row = (unsigned short*)alloc(2048);
  int* amb_count         = (int*)alloc(256);
  int* amb2_count        = (int*)alloc(256);
  // aliased pool: Ahi (tiled) lives until k_gemm1 completes; hbufT/eo written after.
  size_t poolBytes = 2 * (size_t)T_TOK * CDIM * 2;    // 201.3 MB
  char* pool = (char*)alloc(poolBytes);
  unsigned short* Ahi = (unsigned short*)pool;
  size_t poff = 0;
  auto palloc = [&](size_t b) -> void* {
    void* p = pool + poff;
    poff += (b + 255) & ~(size_t)255;
    return p;
  };
  unsigned short* hbufT  = (unsigned short*)palloc((size_t)MAXTILE * 32 * 4096 * 2);
  unsigned short* eo     = (unsigned short*)palloc((size_t)NSLOT * DDIM * 2);
  (void)ws_size; (void)in_sizes; (void)n_in; (void)out_size;

  k_init<<<64, 256, 0, stream>>>(token_list, counts, cursors, zero_row, amb_count, amb2_count);
  k_cast_tiled<<<dim3(128, 24), 256, 0, stream>>>(hidden, Ahi);
  k_transpose_split<<<dim3(12, 24), 256, 0, stream>>>(proj_w, pwT_hi, pwT_lo);
  k_transpose_tiled<<<dim3(16, 6, 8), 256, 0, stream>>>(w1, w1T, DDIM, HDIM);
  k_transpose_tiled<<<dim3(12, 8, 8), 256, 0, stream>>>(w2, w2T, HDIM, DDIM);
  k_gemm1<<<768, 256, 0, stream>>>(Ahi, pwT_hi, xw);
  k_ln_router<<<T_TOK / 4, 256, 0, stream>>>(xw, proj_b, ln1_g, ln1_b, gate_w, gate_b,
                                             seqb, top_i, top_w, amb_list, amb_count);
  k_repair<<<dim3(6, AMB_CAP / 128, KSPLIT), 256, 0, stream>>>(hidden, pwT_hi, pwT_lo,
                                                               amb_list, amb_count, xw_fix4);
  k_fix2<<<AMB_CAP / 4, 256, 0, stream>>>(xw_fix4, proj_b, ln1_g, ln1_b, gate_w, gate_b,
                                          amb_list, amb_count, top_i, top_w,
                                          amb2_list, amb2_count);
  k_router_fix<<<dim3(64, NSEG), 256, 0, stream>>>(hidden, proj_w, amb2_list, amb2_count, xpart);
  k_fix3<<<AMB2_CAP, 256, 0, stream>>>(xpart, proj_b, ln1_g, ln1_b, gate_w, gate_b,
                                       amb2_list, amb2_count, top_i, top_w);
  k_count<<<64, 256, 0, stream>>>(top_i, counts);
  k_offsets<<<1, 64, 0, stream>>>(counts, seg_start, padded_total, tile_expert);
  k_scatter<<<64, 256, 0, stream>>>(top_i, seg_start, cursors, token_list, slot_of);
  k_gemm2<<<MAXTILE * 8, 256, 0, stream>>>(seqb, w1T, b1, token_list, zero_row,
                                           tile_expert, padded_total, hbufT);
  k_gemm3<<<MAXTILE * 6, 256, 0, stream>>>(hbufT, w2T, b2, tile_expert, padded_total, eo);
  k_combine<<<T_TOK / 4, 256, 0, stream>>>(eo, seqb, slot_of, top_w, ln2_g, ln2_b,
                                           cls_w, cls_b, out);
}